// Round 8
// baseline (161.473 us; speedup 1.0000x reference)
//
#include <hip/hip_runtime.h>
#include <stdint.h>

typedef unsigned short u16;
typedef float  f32x4  __attribute__((ext_vector_type(4)));
typedef __bf16 bf16x8 __attribute__((ext_vector_type(8)));
typedef __bf16 bf16x4 __attribute__((ext_vector_type(4)));
typedef unsigned short u16x8 __attribute__((ext_vector_type(8)));
typedef unsigned short u16x4v __attribute__((ext_vector_type(4)));

#define S_LEN 2048
#define E_DIM 2048
#define HD    128
#define QH    16
#define KVH   4
#define KVD   512
#define NQKV  3072
#define QK_SCALE 0.08838834764831845f  // 1/sqrt(128)

#define AS1 __attribute__((address_space(1)))
#define AS3 __attribute__((address_space(3)))

__device__ __forceinline__ u16 f2bf(float f) {
  union { float f; uint32_t u; } v; v.f = f;
  return (u16)((v.u + 0x7FFFu + ((v.u >> 16) & 1u)) >> 16);
}
__device__ __forceinline__ float bf2f(u16 b) {
  union { uint32_t u; float f; } v; v.u = ((uint32_t)b) << 16;
  return v.f;
}

// ---------------- fused cast fp32 -> bf16 for all 5 tensors ----------------
__global__ void cast_all_kernel(const float* __restrict__ x, const float* __restrict__ Wq,
                                const float* __restrict__ Wk, const float* __restrict__ Wv,
                                const float* __restrict__ Wo,
                                u16* __restrict__ xb, u16* __restrict__ Wcat,
                                u16* __restrict__ Wob) {
  int i = blockIdx.x * blockDim.x + threadIdx.x;
  const float* src; u16* dst;
  if (i < (1 << 20))                       { src = x  + (size_t)i * 4;  dst = xb + (size_t)i * 4; }
  else if (i < (2 << 20))                  { size_t j = i - (1 << 20);  src = Wq + j * 4; dst = Wcat + j * 4; }
  else if (i < (2 << 20) + (1 << 18))      { size_t j = i - (2 << 20);  src = Wk + j * 4; dst = Wcat + (size_t)E_DIM * E_DIM + j * 4; }
  else if (i < (2 << 20) + (2 << 18))      { size_t j = i - (2 << 20) - (1 << 18); src = Wv + j * 4; dst = Wcat + (size_t)(E_DIM + KVD) * E_DIM + j * 4; }
  else                                     { size_t j = i - (2 << 20) - (2 << 18); src = Wo + j * 4; dst = Wob + j * 4; }
  float4 f = *reinterpret_cast<const float4*>(src);
  u16x4v o;
  o[0] = f2bf(f.x); o[1] = f2bf(f.y); o[2] = f2bf(f.z); o[3] = f2bf(f.w);
  *reinterpret_cast<u16x4v*>(dst) = o;
}

// ---------------- GEMM: C[M,N] = A[M,K] * B[N,K]^T (+bias), bf16 in ----------
template<bool BIAS, bool OBF16>
__global__ __launch_bounds__(256) void gemm_bt_kernel(
    const u16* __restrict__ A, const u16* __restrict__ B,
    void* __restrict__ Cv, const float* __restrict__ bias,
    int M, int N, int K)
{
  __shared__ u16 As[2][128 * 64];
  __shared__ u16 Bs[2][128 * 64];

  const int tid  = threadIdx.x;
  const int lane = tid & 63;
  const int wid  = tid >> 6;
  const int wr   = (wid >> 1) * 64;
  const int wc   = (wid & 1) * 64;
  const int lr   = lane & 15;
  const int kg   = lane >> 4;

  const int bm = blockIdx.y * 128;
  const int bn = blockIdx.x * 128;

  f32x4 acc[4][4];
  #pragma unroll
  for (int r = 0; r < 4; ++r)
    #pragma unroll
    for (int c = 0; c < 4; ++c) acc[r][c] = (f32x4){0.f, 0.f, 0.f, 0.f};

  const int l8 = lane & 7;
  const int l3 = lane >> 3;
  const int schunk = l8 ^ l3;

  const u16* gA = A + (size_t)(bm + wid*32 + l3) * K + schunk * 8;
  const u16* gB = B + (size_t)(bn + wid*32 + l3) * K + schunk * 8;

  const int sw = lr & 7;

  auto stage = [&](int buf, int kt) {
    #pragma unroll
    for (int i = 0; i < 4; ++i) {
      __builtin_amdgcn_global_load_lds(
          (const AS1 void*)(gA + (size_t)i * 8 * K + kt),
          (AS3 void*)(&As[buf][wid*32*64 + i*8*64]), 16, 0, 0);
      __builtin_amdgcn_global_load_lds(
          (const AS1 void*)(gB + (size_t)i * 8 * K + kt),
          (AS3 void*)(&Bs[buf][wid*32*64 + i*8*64]), 16, 0, 0);
    }
  };

  stage(0, 0);
  __syncthreads();

  int cur = 0;
  for (int kt = 0; kt < K; kt += 64) {
    if (kt + 64 < K) stage(cur ^ 1, kt + 64);
    #pragma unroll
    for (int kk = 0; kk < 2; ++kk) {
      bf16x8 af[4], bfr[4];
      #pragma unroll
      for (int r = 0; r < 4; ++r)
        af[r] = *reinterpret_cast<const bf16x8*>(
            &As[cur][(wr + r*16 + lr)*64 + ((kk*4 + kg) ^ sw)*8]);
      #pragma unroll
      for (int c = 0; c < 4; ++c)
        bfr[c] = *reinterpret_cast<const bf16x8*>(
            &Bs[cur][(wc + c*16 + lr)*64 + ((kk*4 + kg) ^ sw)*8]);
      #pragma unroll
      for (int r = 0; r < 4; ++r)
        #pragma unroll
        for (int c = 0; c < 4; ++c)
          acc[r][c] = __builtin_amdgcn_mfma_f32_16x16x32_bf16(af[r], bfr[c], acc[r][c], 0, 0, 0);
    }
    __syncthreads();
    cur ^= 1;
  }

  const int crow = kg * 4;
  #pragma unroll
  for (int r = 0; r < 4; ++r) {
    #pragma unroll
    for (int c = 0; c < 4; ++c) {
      int gr = bm + wr + r*16 + crow;
      int gc = bn + wc + c*16 + lr;
      float badd = BIAS ? bias[gc] : 0.0f;
      #pragma unroll
      for (int reg = 0; reg < 4; ++reg) {
        float v = acc[r][c][reg] + badd;
        if constexpr (OBF16)
          ((u16*)Cv)[(size_t)(gr + reg)*N + gc] = f2bf(v);
        else
          ((float*)Cv)[(size_t)(gr + reg)*N + gc] = v;
      }
    }
  }
}

// ---------------- RoPE + split qkv_bf16 -> q_bf16 (scaled), k_bf16 -------------
__global__ void rope_split_kernel(const u16* __restrict__ qkv,
                                  u16* __restrict__ qb, u16* __restrict__ kb) {
  int idx = blockIdx.x * blockDim.x + threadIdx.x;
  int s  = idx / 1280;
  int cp = idx - s * 1280;
  int col = cp * 2;
  const u16* src = qkv + (size_t)s * NQKV + col;
  float x0 = bf2f(src[0]), x1 = bf2f(src[1]);
  int p = (col & 127) >> 1;
  float inv = exp2f((float)p * (-13.287712379549449f / 64.0f));
  float ang = (float)s * inv;
  float sn, cs;
  sincosf(ang, &sn, &cs);
  float o0 = x0 * cs - x1 * sn;
  float o1 = x0 * sn + x1 * cs;
  if (col < E_DIM) {
    o0 *= QK_SCALE; o1 *= QK_SCALE;
    qb[(size_t)s * E_DIM + col]     = f2bf(o0);
    qb[(size_t)s * E_DIM + col + 1] = f2bf(o1);
  } else {
    kb[(size_t)s * KVD + (col - E_DIM)]     = f2bf(o0);
    kb[(size_t)s * KVD + (col - E_DIM) + 1] = f2bf(o1);
  }
}

// ---------------- V transpose: qkv bf16 v-block (S x 512) -> vT (512 x S) ------
__global__ void transpose_v_kernel(const u16* __restrict__ qkv, u16* __restrict__ vT) {
  __shared__ u16 tile[32][33];
  const int sbase = blockIdx.x * 32;
  const int cbase = blockIdx.y * 32;
  const int tx = threadIdx.x;
  const int ty = threadIdx.y;
  #pragma unroll
  for (int i = 0; i < 32; i += 8)
    tile[ty + i][tx] = qkv[(size_t)(sbase + ty + i) * NQKV + (E_DIM + KVD) + cbase + tx];
  __syncthreads();
  #pragma unroll
  for (int i = 0; i < 32; i += 8)
    vT[(size_t)(cbase + ty + i) * S_LEN + sbase + tx] = tile[tx][ty + i];
}

// ---------------- Flash attention (causal, GQA 4:1), split-KV in-block ---------
// 512 threads = 2 groups x 4 waves. Group g handles kv-tiles t==g (mod 2) with
// its own Ks dbuf + VTs (r7-validated structure), keeping partial (m,l,O).
// Final online-softmax merge via LDS (group1 -> retired Ks buffer as f32 O).
// Critical path: 32 -> 16 serial tiles for qt=31. Grid 512: round1 = long
// halves (qt 31..16), round2 = short halves longest-first (qt 15..0).
__global__ __launch_bounds__(512, 1) void attn_kernel(
    const u16* __restrict__ Q, const u16* __restrict__ Kc,
    const u16* __restrict__ VT, u16* __restrict__ Out)
{
  __shared__ u16 Ks[2][2][64 * 128];   // [grp][buf] 16KB each = 64 KB
  __shared__ u16 VTs[2][128 * 64];     // [grp] 16 KB each = 32 KB
  __shared__ u16 Ps[8][16 * 72];       // per-wave P staging, 18.4 KB
  __shared__ float Lm[4][16], Ll[4][16];

  const int x = blockIdx.x;
  int qt, h;
  if (x < 256) { qt = 31 - (x & 15); h = x >> 4; }
  else         { int y = x - 256; qt = 15 - (y & 15); h = y >> 4; }
  const int kvh = h >> 2;

  const int tid  = threadIdx.x;
  const int lane = tid & 63;
  const int wid  = tid >> 6;    // 0..7
  const int grp  = wid >> 2;    // kv-parity group
  const int wl   = wid & 3;     // wave-in-group: q rows wl*16..+16
  const int ltid = tid & 255;   // thread-in-group
  const int lr   = lane & 15;
  const int kg   = lane >> 4;
  const int sw   = lr & 7;

  const int NT = qt + 1;
  const int NI = (NT + 1) >> 1;   // group0 tile count = barrier-loop count

  bf16x8 qf[4];
  {
    const u16* qa = Q + (size_t)(qt*64 + wl*16 + lr) * E_DIM + h * HD + kg * 8;
    #pragma unroll
    for (int kk = 0; kk < 4; ++kk)
      qf[kk] = *reinterpret_cast<const bf16x8*>(qa + kk * 32);
  }

  f32x4 o[8];
  #pragma unroll
  for (int d = 0; d < 8; ++d) o[d] = (f32x4){0.f,0.f,0.f,0.f};
  float mr = -1e30f, ls = 0.f;

  const u16* kbase = Kc + kvh * HD;
  const u16* vbase = VT + (size_t)(kvh * HD) * S_LEN;
  u16* ps = Ps[wid];

  // K tile DMA (16KB per group tile): group's 4 waves, issue j covers rows
  // j*16+wl*4..+4. lane l -> row +(l>>4), slot l&15; src chunk = (l&15)^(row&7).
  const int kr_off = lane >> 4;
  const int kchunk = lane & 15;
  auto k_dma = [&](int buf, int t) {
    #pragma unroll
    for (int j = 0; j < 4; ++j) {
      int r0 = j*16 + wl*4;
      int r  = r0 + kr_off;
      const u16* src = kbase + (size_t)(t*64 + r) * KVD + ((kchunk ^ (r & 7)) * 8);
      __builtin_amdgcn_global_load_lds((const AS1 void*)src,
          (AS3 void*)(&Ks[grp][buf][r0 * 128]), 16, 0, 0);
    }
  };

  // V global->reg (coalesced along kv); reg->VTs[grp] with chunk^(d&7).
  u16x8 vreg[4];
  auto v_load = [&](int t) {
    #pragma unroll
    for (int i = 0; i < 4; ++i) {
      int c = i * 256 + ltid;
      vreg[i] = *reinterpret_cast<const u16x8*>(
          vbase + (size_t)(c >> 3) * S_LEN + t*64 + (c & 7) * 8);
    }
  };
  auto v_write = [&]() {
    #pragma unroll
    for (int i = 0; i < 4; ++i) {
      int c = i * 256 + ltid;
      int d = c >> 3;
      *reinterpret_cast<u16x8*>(&VTs[grp][d*64 + ((c & 7) ^ (d & 7)) * 8]) = vreg[i];
    }
  };

  if (grp < NT) {           // group1 idle-prologue only when NT==1
    k_dma(0, grp);
    v_load(grp);
    v_write();
  }
  __syncthreads();

  int p = 0;
  for (int i = 0; i < NI; ++i) {
    const int t = 2*i + grp;
    const bool valid = t < NT;
    const bool hn = t + 2 < NT;
    if (valid && hn) { k_dma(p ^ 1, t + 2); v_load(t + 2); }

    if (valid) {
      // S^T = mfma(K, Q): lane (lr,kg) holds S[kv=c*16+kg*4+reg][q=lr]
      f32x4 st[4];
      #pragma unroll
      for (int c = 0; c < 4; ++c) st[c] = (f32x4){0.f, 0.f, 0.f, 0.f};
      __builtin_amdgcn_s_setprio(1);
      #pragma unroll
      for (int kk = 0; kk < 4; ++kk) {
        #pragma unroll
        for (int c = 0; c < 4; ++c) {
          bf16x8 kfr = *reinterpret_cast<const bf16x8*>(
              &Ks[grp][p][(c*16 + lr)*128 + ((kk*4 + kg) ^ sw)*8]);
          st[c] = __builtin_amdgcn_mfma_f32_16x16x32_bf16(kfr, qf[kk], st[c], 0, 0, 0);
        }
      }
      __builtin_amdgcn_s_setprio(0);

      if (t == qt) {  // diagonal tile (belongs to group qt&1)
        #pragma unroll
        for (int c = 0; c < 4; ++c)
          #pragma unroll
          for (int reg = 0; reg < 4; ++reg)
            if (c*16 + kg*4 + reg > wl*16 + lr) st[c][reg] = -1e30f;
      }

      float cm[4];
      #pragma unroll
      for (int c = 0; c < 4; ++c)
        cm[c] = fmaxf(fmaxf(st[c][0], st[c][1]), fmaxf(st[c][2], st[c][3]));
      float pm = fmaxf(fmaxf(cm[0], cm[1]), fmaxf(cm[2], cm[3]));
      pm = fmaxf(pm, __shfl_xor(pm, 16));
      pm = fmaxf(pm, __shfl_xor(pm, 32));

      if (!__all(pm - mr <= 8.0f)) {  // defer-max rescale (rare)
        float nm = fmaxf(mr, pm);
        float alpha = __expf(mr - nm);
        ls *= alpha;
        mr = nm;
        float ar[4];
        #pragma unroll
        for (int reg = 0; reg < 4; ++reg)
          ar[reg] = __shfl(alpha, kg*4 + reg);
        #pragma unroll
        for (int d = 0; d < 8; ++d)
          #pragma unroll
          for (int reg = 0; reg < 4; ++reg)
            o[d][reg] *= ar[reg];
      }

      float sum = 0.f;
      #pragma unroll
      for (int c = 0; c < 4; ++c) {
        float pr[4];
        #pragma unroll
        for (int reg = 0; reg < 4; ++reg)
          pr[reg] = __expf(st[c][reg] - mr);
        sum += (pr[0] + pr[1]) + (pr[2] + pr[3]);
        bf16x4 pk;
        #pragma unroll
        for (int reg = 0; reg < 4; ++reg) pk[reg] = (__bf16)pr[reg];
        *reinterpret_cast<bf16x4*>(&ps[lr*72 + c*16 + kg*4]) = pk;
      }
      sum += __shfl_xor(sum, 16);
      sum += __shfl_xor(sum, 32);
      ls += sum;

      bf16x8 pa[2];
      #pragma unroll
      for (int kk = 0; kk < 2; ++kk)
        pa[kk] = *reinterpret_cast<const bf16x8*>(&ps[lr*72 + kk*32 + kg*8]);
      __builtin_amdgcn_s_setprio(1);
      #pragma unroll
      for (int d0 = 0; d0 < 8; ++d0) {
        #pragma unroll
        for (int kk = 0; kk < 2; ++kk) {
          bf16x8 vb = *reinterpret_cast<const bf16x8*>(
              &VTs[grp][(d0*16 + lr)*64 + ((kk*4 + kg) ^ sw)*8]);
          o[d0] = __builtin_amdgcn_mfma_f32_16x16x32_bf16(pa[kk], vb, o[d0], 0, 0, 0);
        }
      }
      __builtin_amdgcn_s_setprio(0);
    }

    if (i + 1 < NI) {
      __syncthreads();        // group done reading VTs/Ks; drains K-DMA(t+2)
      if (hn) v_write();      // V(t+2) -> VTs[grp]
      __syncthreads();        // VTs visible
      p ^= 1;
    }
  }

  // -------- cross-group merge: group1 publishes, group0 combines+writes ------
  __syncthreads();                       // all compute done; Ks reusable
  float* Obuf = (float*)&Ks[0][0][0];    // 64 x 128 f32 = 32 KB
  if (grp == 1) {
    if (kg == 0) { Lm[wl][lr] = mr; Ll[wl][lr] = ls; }
    #pragma unroll
    for (int reg = 0; reg < 4; ++reg) {
      int rrow = wl*16 + kg*4 + reg;
      #pragma unroll
      for (int d = 0; d < 8; ++d)
        Obuf[rrow*128 + d*16 + lr] = o[d][reg];
    }
  }
  __syncthreads();
  if (grp == 0) {
    float m0r[4], l0r[4];
    #pragma unroll
    for (int reg = 0; reg < 4; ++reg) {
      m0r[reg] = __shfl(mr, kg*4 + reg);
      l0r[reg] = __shfl(ls, kg*4 + reg);
    }
    #pragma unroll
    for (int reg = 0; reg < 4; ++reg) {
      int rloc = kg*4 + reg;
      float m1 = Lm[wl][rloc], l1 = Ll[wl][rloc];
      float m  = fmaxf(m0r[reg], m1);
      float a0 = __expf(m0r[reg] - m);
      float a1 = __expf(m1 - m);
      float inv = 1.0f / (l0r[reg]*a0 + l1*a1);
      int grow = qt*64 + wl*16 + rloc;
      #pragma unroll
      for (int d = 0; d < 8; ++d) {
        float v = (o[d][reg]*a0 + Obuf[(wl*16 + rloc)*128 + d*16 + lr]*a1) * inv;
        Out[(size_t)grow * E_DIM + h * HD + d*16 + lr] =
            __builtin_bit_cast(u16, (__bf16)v);
      }
    }
  }
}

// ---------------- launch ----------------
extern "C" void kernel_launch(void* const* d_in, const int* in_sizes, int n_in,
                              void* d_out, int out_size, void* d_ws, size_t ws_size,
                              hipStream_t stream)
{
  const float* x  = (const float*)d_in[0];
  const float* Wq = (const float*)d_in[1];
  const float* Wk = (const float*)d_in[2];
  const float* Wv = (const float*)d_in[3];
  const float* Wo = (const float*)d_in[4];
  const float* bo = (const float*)d_in[5];
  float* out = (float*)d_out;

  char* w = (char*)d_ws;
  u16*   xb   = (u16*)(w);                   // 8 MB  x bf16 (2048x2048)
  u16*   Wcat = (u16*)(w + (8u  << 20));     // 12 MB [Wq;Wk;Wv] bf16 (3072x2048)
  u16*   Wob  = (u16*)(w + (20u << 20));     // 8 MB  Wo bf16
  u16*   qkv  = (u16*)(w + (28u << 20));     // 12 MB qkv bf16 (2048x3072)
  u16*   qb   = (u16*)(w + (52u << 20));     // 8 MB  q bf16 roped+scaled
  u16*   kb   = (u16*)(w + (60u << 20));     // 2 MB  k bf16 roped
  u16*   vT   = (u16*)(w + (62u << 20));     // 2 MB  v^T bf16 (512x2048)
  u16*   attn = (u16*)(w + (64u << 20));     // 8 MB  attention out bf16
  (void)ws_size; (void)in_sizes; (void)n_in; (void)out_size;

  cast_all_kernel<<<14336, 256, 0, stream>>>(x, Wq, Wk, Wv, Wo, xb, Wcat, Wob);

  gemm_bt_kernel<false, true><<<dim3(NQKV/128, S_LEN/128), 256, 0, stream>>>(
      xb, Wcat, qkv, nullptr, S_LEN, NQKV, E_DIM);

  rope_split_kernel<<<(S_LEN * 1280) / 256, 256, 0, stream>>>(qkv, qb, kb);
  transpose_v_kernel<<<dim3(S_LEN/32, KVD/32), dim3(32, 8), 0, stream>>>(qkv, vT);

  attn_kernel<<<512, 512, 0, stream>>>(qb, kb, vT, attn);

  gemm_bt_kernel<true, false><<<dim3(E_DIM/128, S_LEN/128), 256, 0, stream>>>(
      attn, Wob, out, bo, S_LEN, E_DIM, E_DIM);
}